// Round 2
// baseline (965.364 us; speedup 1.0000x reference)
//
#include <hip/hip_runtime.h>

#define T_LEN 16000
#define SEG_L 63
#define NSEG 254          // ceil(16000/63); 254*63 = 16002 (2 padded steps, never consumed)
#define ROWS 4096

// High-pass biquad (fixed): a = (-1.99599, 0.996), b = (-2, 1)
#define HP_NA0  1.99599f   // -a0
#define HP_NA1 -0.996f     // -a1
#define HP_B0  -2.0f
#define HP_B1   1.0f

__device__ __forceinline__ void mm4(const float* A, const float* B, float* C) {
#pragma unroll
  for (int r = 0; r < 4; ++r) {
#pragma unroll
    for (int c = 0; c < 4; ++c) {
      float s = 0.f;
#pragma unroll
      for (int k = 0; k < 4; ++k) s = fmaf(A[r * 4 + k], B[k * 4 + c], s);
      C[r * 4 + c] = s;
    }
  }
}

// Per path p in {0=x,1=n}: P_k = (M^63)^(2^k), k = 0..7, into ws[p*128 + k*16].
// M = 4-state transition of the cascade, state s = (p0,p1,q0,q1):
//   y1 = x + p0; y2 = y1 + q0 (DF2T states of the two biquads).
__global__ void setup_kernel(const float* __restrict__ a_x, const float* __restrict__ b_x,
                             const float* __restrict__ a_n, const float* __restrict__ b_n,
                             float* __restrict__ ws) {
  int p = threadIdx.x;
  if (p >= 2) return;
  const float* a = p ? a_n : a_x;
  const float* b = p ? b_n : b_x;
  float a0 = a[0], a1 = a[1], b0 = b[0], b1 = b[1];

  float M[16] = {
      HP_NA0,   1.f, 0.f,  0.f,
      HP_NA1,   0.f, 0.f,  0.f,
      b0 - a0,  0.f, -a0,  1.f,
      b1 - a1,  0.f, -a1,  0.f};

  float cur[16], res[16], tmp[16];
#pragma unroll
  for (int i = 0; i < 16; ++i) { cur[i] = M[i]; res[i] = M[i]; }
  // res = M^63 = M^(1+2+4+8+16+32)
  for (int s = 0; s < 5; ++s) {
    mm4(cur, cur, tmp);
#pragma unroll
    for (int i = 0; i < 16; ++i) cur[i] = tmp[i];
    mm4(res, cur, tmp);
#pragma unroll
    for (int i = 0; i < 16; ++i) res[i] = tmp[i];
  }
  float* dst = ws + p * 128;
#pragma unroll
  for (int i = 0; i < 16; ++i) dst[i] = res[i];
  for (int k = 1; k < 8; ++k) {
    mm4(res, res, tmp);
#pragma unroll
    for (int i = 0; i < 16; ++i) { res[i] = tmp[i]; dst[k * 16 + i] = res[i]; }
  }
}

__launch_bounds__(256)
__global__ void filt_kernel(const float* __restrict__ x, const float* __restrict__ n,
                            const float* __restrict__ a_x, const float* __restrict__ b_x,
                            const float* __restrict__ a_n, const float* __restrict__ b_n,
                            const float* __restrict__ ws, float* __restrict__ out) {
  __shared__ float buf[T_LEN];        // 64000 B: the row (input, then output in-place)
  __shared__ float sd[NSEG * 5 + 2];  // scan states, stride 5 (coprime w/ 32 banks)
  __shared__ float Pm[128];           // the 8 scan matrices for this path

  const int bid = blockIdx.x;
  const int path = bid >> 12;   // 4096 rows per path
  const int row = bid & 4095;
  const int tid = threadIdx.x;

  const float* src = (path ? n : x) + (size_t)row * T_LEN;
  float* dst = out + (size_t)path * ((size_t)ROWS * T_LEN) + (size_t)row * T_LEN;

  // stage: row -> LDS (coalesced float4), matrices -> LDS
  const float4* s4 = reinterpret_cast<const float4*>(src);
  float4* b4 = reinterpret_cast<float4*>(buf);
  for (int i = tid; i < T_LEN / 4; i += 256) b4[i] = s4[i];
  if (tid < 128) Pm[tid] = ws[path * 128 + tid];

  // second-biquad coefficients (wave-uniform scalar loads)
  const float* aa = path ? a_n : a_x;
  const float* bb = path ? b_n : b_x;
  const float a0r = aa[0], a1r = aa[1], b0r = bb[0], b1r = bb[1];
  const float na0r = -a0r, na1r = -a1r;
  __syncthreads();

  const int t = tid;

  // ---- pass 1: per-segment affine offset D_t = F_t(0) ----
  float p0 = 0.f, p1 = 0.f, q0 = 0.f, q1 = 0.f;
  if (t < NSEG) {
    const int base = t * SEG_L;
    for (int j = 0; j < SEG_L; ++j) {
      const int idx = base + j;
      const float xv = (idx < T_LEN) ? buf[idx] : 0.f;  // padded steps: x = 0
      const float y1 = xv + p0;
      const float np0 = fmaf(HP_NA0, y1, fmaf(HP_B0, xv, p1));
      p1 = fmaf(HP_NA1, y1, HP_B1 * xv);
      p0 = np0;
      const float y2 = y1 + q0;
      const float nq0 = fmaf(na0r, y2, fmaf(b0r, y1, q1));
      q1 = fmaf(na1r, y2, b1r * y1);
      q0 = nq0;
    }
    sd[t * 5 + 0] = p0; sd[t * 5 + 1] = p1; sd[t * 5 + 2] = q0; sd[t * 5 + 3] = q1;
  }
  __syncthreads();

  // ---- Kogge-Stone inclusive scan: D_t += (M^63)^(2^k) * D_{t-2^k} ----
  float d0 = p0, d1 = p1, d2 = q0, d3 = q1;
  for (int k = 0; k < 8; ++k) {
    const int o = 1 << k;
    float v0 = 0.f, v1 = 0.f, v2 = 0.f, v3 = 0.f;
    const bool act = (t < NSEG) && (t >= o);
    if (act) {
      v0 = sd[(t - o) * 5 + 0]; v1 = sd[(t - o) * 5 + 1];
      v2 = sd[(t - o) * 5 + 2]; v3 = sd[(t - o) * 5 + 3];
    }
    __syncthreads();  // all reads done before writes
    if (act) {
      const float* P = Pm + k * 16;
      d0 = fmaf(P[0],  v0, fmaf(P[1],  v1, fmaf(P[2],  v2, fmaf(P[3],  v3, d0))));
      d1 = fmaf(P[4],  v0, fmaf(P[5],  v1, fmaf(P[6],  v2, fmaf(P[7],  v3, d1))));
      d2 = fmaf(P[8],  v0, fmaf(P[9],  v1, fmaf(P[10], v2, fmaf(P[11], v3, d2))));
      d3 = fmaf(P[12], v0, fmaf(P[13], v1, fmaf(P[14], v2, fmaf(P[15], v3, d3))));
      sd[t * 5 + 0] = d0; sd[t * 5 + 1] = d1; sd[t * 5 + 2] = d2; sd[t * 5 + 3] = d3;
    }
    __syncthreads();  // writes visible for next step
  }

  // ---- pass 2: replay segment with true incoming state; write y in-place ----
  if (t < NSEG) {
    float sp0 = 0.f, sp1 = 0.f, sq0 = 0.f, sq1 = 0.f;
    if (t > 0) {
      sp0 = sd[(t - 1) * 5 + 0]; sp1 = sd[(t - 1) * 5 + 1];
      sq0 = sd[(t - 1) * 5 + 2]; sq1 = sd[(t - 1) * 5 + 3];
    }
    const int base = t * SEG_L;
    const int lim = min(SEG_L, T_LEN - base);
    for (int j = 0; j < lim; ++j) {
      const int idx = base + j;
      const float xv = buf[idx];
      const float y1 = xv + sp0;
      const float np0 = fmaf(HP_NA0, y1, fmaf(HP_B0, xv, sp1));
      sp1 = fmaf(HP_NA1, y1, HP_B1 * xv);
      sp0 = np0;
      const float y2 = y1 + sq0;
      const float nq0 = fmaf(na0r, y2, fmaf(b0r, y1, sq1));
      sq1 = fmaf(na1r, y2, b1r * y1);
      sq0 = nq0;
      buf[idx] = y2;  // own segment only: no cross-thread hazard
    }
  }
  __syncthreads();

  // store: LDS -> global (coalesced float4)
  float4* d4 = reinterpret_cast<float4*>(dst);
  for (int i = tid; i < T_LEN / 4; i += 256) d4[i] = b4[i];
}

extern "C" void kernel_launch(void* const* d_in, const int* in_sizes, int n_in,
                              void* d_out, int out_size, void* d_ws, size_t ws_size,
                              hipStream_t stream) {
  const float* x   = (const float*)d_in[0];
  const float* n   = (const float*)d_in[1];
  const float* a_x = (const float*)d_in[2];
  const float* b_x = (const float*)d_in[3];
  const float* a_n = (const float*)d_in[4];
  const float* b_n = (const float*)d_in[5];
  float* out = (float*)d_out;
  float* ws  = (float*)d_ws;

  hipLaunchKernelGGL(setup_kernel, dim3(1), dim3(64), 0, stream, a_x, b_x, a_n, b_n, ws);
  hipLaunchKernelGGL(filt_kernel, dim3(2 * ROWS), dim3(256), 0, stream,
                     x, n, a_x, b_x, a_n, b_n, ws, out);
}

// Round 8
// 851.165 us; speedup vs baseline: 1.1342x; 1.1342x over previous
//
#include <hip/hip_runtime.h>

#define T_LEN 16000
#define HALF  8000
#define SEG_L 33
#define NSEG  243          // ceil(8000/33); 243*33 = 8019 (19 padded steps, never consumed)
#define ROWS  4096

// High-pass biquad (fixed): a = (-1.99599, 0.996), b = (-2, 1)
#define HP_NA0  1.99599f   // -a0
#define HP_NA1 -0.996f     // -a1
#define HP_B0  -2.0f
#define HP_B1   1.0f

__device__ __forceinline__ void mm4(const float* A, const float* B, float* C) {
#pragma unroll
  for (int r = 0; r < 4; ++r) {
#pragma unroll
    for (int c = 0; c < 4; ++c) {
      float s = 0.f;
#pragma unroll
      for (int k = 0; k < 4; ++k) s = fmaf(A[r * 4 + k], B[k * 4 + c], s);
      C[r * 4 + c] = s;
    }
  }
}

// Per path p in {0=x,1=n}: P_k = (M^33)^(2^k), k = 0..7, into ws[p*128 + k*16].
// M = 4-state transition of the cascade, state s = (p0,p1,q0,q1).
__global__ void setup_kernel(const float* __restrict__ a_x, const float* __restrict__ b_x,
                             const float* __restrict__ a_n, const float* __restrict__ b_n,
                             float* __restrict__ ws) {
  int p = threadIdx.x;
  if (p >= 2) return;
  const float* a = p ? a_n : a_x;
  const float* b = p ? b_n : b_x;
  float a0 = a[0], a1 = a[1], b0 = b[0], b1 = b[1];

  float M[16] = {
      HP_NA0,   1.f, 0.f,  0.f,
      HP_NA1,   0.f, 0.f,  0.f,
      b0 - a0,  0.f, -a0,  1.f,
      b1 - a1,  0.f, -a1,  0.f};

  // res = M^33 (repeated multiply; tiny kernel, cost irrelevant)
  float res[16], tmp[16];
#pragma unroll
  for (int i = 0; i < 16; ++i) res[i] = M[i];
  for (int s = 1; s < SEG_L; ++s) {
    mm4(res, M, tmp);
#pragma unroll
    for (int i = 0; i < 16; ++i) res[i] = tmp[i];
  }
  float* dst = ws + p * 128;
#pragma unroll
  for (int i = 0; i < 16; ++i) dst[i] = res[i];
  for (int k = 1; k < 8; ++k) {
    mm4(res, res, tmp);
#pragma unroll
    for (int i = 0; i < 16; ++i) { res[i] = tmp[i]; dst[k * 16 + i] = res[i]; }
  }
}

__launch_bounds__(256)
__global__ void filt_kernel(const float* __restrict__ x, const float* __restrict__ n,
                            const float* __restrict__ a_x, const float* __restrict__ b_x,
                            const float* __restrict__ a_n, const float* __restrict__ b_n,
                            const float* __restrict__ ws, float* __restrict__ out) {
  __shared__ float  buf[HALF];       // 32000 B: half-row (input, then output in-place)
  __shared__ float4 sd[2][NSEG];     // ping-pong scan states, 7776 B
  __shared__ float  Pm[128];         // 8 scan matrices for this path
  __shared__ float  carry[4];        // exact state at the half boundary

  const int bid = blockIdx.x;
  const int path = bid >> 12;        // 4096 rows per path
  const int row = bid & 4095;
  const int t = threadIdx.x;

  const float* src = (path ? n : x) + (size_t)row * T_LEN;
  float* dst = out + (size_t)path * ((size_t)ROWS * T_LEN) + (size_t)row * T_LEN;

  if (t < 128) Pm[t] = ws[path * 128 + t];

  // second-biquad coefficients (wave-uniform scalar loads)
  const float* aa = path ? a_n : a_x;
  const float* bb = path ? b_n : b_x;
  const float a0r = aa[0], a1r = aa[1], b0r = bb[0], b1r = bb[1];
  const float na0r = -a0r, na1r = -a1r;

  float i0 = 0.f, i1 = 0.f, i2 = 0.f, i3 = 0.f;   // s_init for the current half

  for (int h = 0; h < 2; ++h) {
    const float* hsrc = src + h * HALF;

    // ---- stage: half-row -> LDS (coalesced float4) ----
    {
      const float4* s4 = reinterpret_cast<const float4*>(hsrc);
      float4* b4 = reinterpret_cast<float4*>(buf);
      for (int i = t; i < HALF / 4; i += 256) b4[i] = s4[i];
    }
    __syncthreads();

    // ---- pass 1: per-segment response; thread 0 seeded with s_init ----
    float p0 = 0.f, p1 = 0.f, q0 = 0.f, q1 = 0.f;
    if (t < NSEG) {
      if (t == 0) { p0 = i0; p1 = i1; q0 = i2; q1 = i3; }
      const int base = t * SEG_L;
      for (int j = 0; j < SEG_L; ++j) {
        const int idx = base + j;
        const float xv = (idx < HALF) ? buf[idx] : 0.f;   // padded steps: x = 0
        const float y1 = xv + p0;
        const float np0 = fmaf(HP_NA0, y1, fmaf(HP_B0, xv, p1));
        p1 = fmaf(HP_NA1, y1, HP_B1 * xv);
        p0 = np0;
        const float y2 = y1 + q0;
        const float nq0 = fmaf(na0r, y2, fmaf(b0r, y1, q1));
        q1 = fmaf(na1r, y2, b1r * y1);
        q0 = nq0;
      }
      sd[0][t] = make_float4(p0, p1, q0, q1);
    }
    __syncthreads();

    // ---- Kogge-Stone scan, ping-pong buffers, 1 barrier/step ----
    // invariant: step k reads sd[cur], writes sd[cur^1]; after 8 steps result is in sd[0]
    float4 d = make_float4(p0, p1, q0, q1);
    int cur = 0;
    for (int k = 0; k < 8; ++k) {
      const int o = 1 << k;
      if (t < NSEG) {
        if (t >= o) {
          const float4 v = sd[cur][t - o];
          const float* P = Pm + k * 16;
          d.x = fmaf(P[0],  v.x, fmaf(P[1],  v.y, fmaf(P[2],  v.z, fmaf(P[3],  v.w, d.x))));
          d.y = fmaf(P[4],  v.x, fmaf(P[5],  v.y, fmaf(P[6],  v.z, fmaf(P[7],  v.w, d.y))));
          d.z = fmaf(P[8],  v.x, fmaf(P[9],  v.y, fmaf(P[10], v.z, fmaf(P[11], v.w, d.z))));
          d.w = fmaf(P[12], v.x, fmaf(P[13], v.y, fmaf(P[14], v.z, fmaf(P[15], v.w, d.w))));
        }
        sd[cur ^ 1][t] = d;
      }
      cur ^= 1;
      __syncthreads();
    }

    // ---- pass 2: replay with true incoming state; write y in-place ----
    if (t < NSEG) {
      float sp0 = i0, sp1 = i1, sq0 = i2, sq1 = i3;
      if (t > 0) {
        const float4 v = sd[0][t - 1];
        sp0 = v.x; sp1 = v.y; sq0 = v.z; sq1 = v.w;
      }
      const int base = t * SEG_L;
      const int lim = min(SEG_L, HALF - base);
      for (int j = 0; j < lim; ++j) {
        const int idx = base + j;
        const float xv = buf[idx];
        const float y1 = xv + sp0;
        const float np0 = fmaf(HP_NA0, y1, fmaf(HP_B0, xv, sp1));
        sp1 = fmaf(HP_NA1, y1, HP_B1 * xv);
        sp0 = np0;
        const float y2 = y1 + sq0;
        const float nq0 = fmaf(na0r, y2, fmaf(b0r, y1, sq1));
        sq1 = fmaf(na1r, y2, b1r * y1);
        sq0 = nq0;
        buf[idx] = y2;   // own segment only: no cross-thread hazard
      }
      if (t == NSEG - 1) {   // last real segment ends exactly at sample HALF-1
        carry[0] = sp0; carry[1] = sp1; carry[2] = sq0; carry[3] = sq1;
      }
    }
    __syncthreads();   // buf + carry visible

    // ---- store: LDS -> global (coalesced float4) ----
    {
      float4* d4 = reinterpret_cast<float4*>(dst) + h * (HALF / 4);
      const float4* b4 = reinterpret_cast<const float4*>(buf);
      for (int i = t; i < HALF / 4; i += 256) d4[i] = b4[i];
    }
    // pick up the exact boundary state for the next half (uniform broadcast read)
    i0 = carry[0]; i1 = carry[1]; i2 = carry[2]; i3 = carry[3];
    __syncthreads();   // store reads done before next stage overwrites buf
  }
}

extern "C" void kernel_launch(void* const* d_in, const int* in_sizes, int n_in,
                              void* d_out, int out_size, void* d_ws, size_t ws_size,
                              hipStream_t stream) {
  const float* x   = (const float*)d_in[0];
  const float* n   = (const float*)d_in[1];
  const float* a_x = (const float*)d_in[2];
  const float* b_x = (const float*)d_in[3];
  const float* a_n = (const float*)d_in[4];
  const float* b_n = (const float*)d_in[5];
  float* out = (float*)d_out;
  float* ws  = (float*)d_ws;

  hipLaunchKernelGGL(setup_kernel, dim3(1), dim3(64), 0, stream, a_x, b_x, a_n, b_n, ws);
  hipLaunchKernelGGL(filt_kernel, dim3(2 * ROWS), dim3(256), 0, stream,
                     x, n, a_x, b_x, a_n, b_n, ws, out);
}